// Round 1
// baseline (167.700 us; speedup 1.0000x reference)
//
#include <hip/hip_runtime.h>

#define BATCH 65536
#define HID 512
#define MT 64                 // rows per block
#define XSS 520               // xs row stride (ushort), 1040B: +4 banks/row -> conflict-free
#define BSS 40                // bs row stride (ushort), 80B: +20 banks/row -> conflict-free

// d_ws layout (ushort offsets)
#define WI_OFF 0              // [512][32]  (k padded 16->32)
#define WH_OFF 16384          // [2][512][512]
#define WO_OFF 540672         // [32][512]  (o padded 17->32)
#define WS_USH 557056
// float region, base = (float*)((char*)ws + WS_USH*2)
#define BI_F 0
#define BH_F 512
#define BO_F 1536
#define ERR_F 1568
#define PREP_TOTAL (WS_USH + 1570)

typedef __bf16 bf16x8 __attribute__((ext_vector_type(8)));
typedef float f32x4 __attribute__((ext_vector_type(4)));

__device__ inline unsigned short f2bf(float f) {
  union { float f; unsigned u; } v; v.f = f;
  unsigned u = v.u + 0x7fffu + ((v.u >> 16) & 1u);   // RNE
  return (unsigned short)(u >> 16);
}

__global__ void prep_kernel(const float* __restrict__ w_in, const float* __restrict__ b_in,
                            const float* __restrict__ w_hid, const float* __restrict__ b_hid,
                            const float* __restrict__ w_out, const float* __restrict__ b_out,
                            const int* __restrict__ variant, int n,
                            unsigned short* __restrict__ wsu, float* __restrict__ wsf)
{
  const int model = (n - 5) * 16 + variant[0];
  const int i = blockIdx.x * 256 + threadIdx.x;
  if (i < 16384) {                      // WI [512][32]
    int h = i >> 5, k = i & 31;
    wsu[WI_OFF + i] = (k < 16) ? f2bf(w_in[(size_t)model * 8192 + h * 16 + k]) : (unsigned short)0;
  } else if (i < 16384 + 524288) {      // WH [2][512][512]
    int j = i - 16384;
    wsu[WH_OFF + j] = f2bf(w_hid[(size_t)model * 524288 + j]);
  } else if (i < WS_USH) {              // WO [32][512]
    int j = i - 540672;
    int o = j >> 9, k = j & 511;
    wsu[WO_OFF + j] = (o < 17) ? f2bf(w_out[(size_t)model * 8704 + o * 512 + k]) : (unsigned short)0;
  } else if (i < PREP_TOTAL) {          // biases + err accumulators
    int j = i - WS_USH;
    if (j < 512)       wsf[BI_F + j] = b_in[(size_t)model * 512 + j];
    else if (j < 1536) wsf[BH_F + (j - 512)] = b_hid[(size_t)model * 1024 + (j - 512)];
    else if (j < 1568) { int o = j - 1536; wsf[BO_F + o] = (o < 17) ? b_out[(size_t)model * 17 + o] : 0.f; }
    else               wsf[ERR_F + (j - 1568)] = 0.f;
  }
}

template<int CN>
__global__ __launch_bounds__(512) void fused_kernel(
    const float* __restrict__ T, const unsigned short* __restrict__ wsu,
    const float* __restrict__ wsf, float* __restrict__ Xout, float* __restrict__ Xcout,
    float* __restrict__ errAcc, int n_arg)
{
  const int n = CN ? CN : n_arg;
  __shared__ unsigned short xs[MT * XSS];          // 66,560 B
  __shared__ unsigned short bs[2 * 512 * BSS];     // 81,920 B
  __shared__ float xo[MT * 20];                    //  5,120 B
  __shared__ float scaleS[MT];                     //    256 B

  const int tid = threadIdx.x;
  const int blk = blockIdx.x;
  const int lane = tid & 63;
  const int wid = tid >> 6;
  const int l15 = lane & 15;
  const int q = lane >> 4;
  const int wm = wid >> 2;   // 0..1
  const int wn = wid & 3;    // 0..3

  f32x4 acc[2][8];
  #pragma unroll
  for (int a = 0; a < 2; ++a)
    #pragma unroll
    for (int b = 0; b < 8; ++b) { f32x4 z = {0.f, 0.f, 0.f, 0.f}; acc[a][b] = z; }

  // ---- prologue: T load + normalize (threads 0..63) ----
  if (tid < MT) {
    const int r = tid;
    const size_t gr = (size_t)blk * MT + r;
    const float* tp = T + gr * n;
    float tv[16]; float ss = 0.f;
    #pragma unroll
    for (int k = 0; k < 16; ++k) { float v = (k < n) ? tp[k] : 0.f; tv[k] = v; ss += v * v; }
    float norm = sqrtf(ss < 1e-12f ? 1e-12f : ss);
    float rn = 1.f / norm;
    scaleS[r] = sqrtf(norm);
    #pragma unroll
    for (int k = 0; k < 16; ++k) xs[r * XSS + k] = f2bf(tv[k] * rn);
    #pragma unroll
    for (int k = 16; k < 32; ++k) xs[r * XSS + k] = 0;
  }

  // ---- stage WH0 slice 0 -> bs[0] ----
  {
    const unsigned short* W = wsu + WH_OFF;
    #pragma unroll
    for (int c = 0; c < 4; ++c) {
      int id = tid + c * 512; int o = id >> 2, g = id & 3;
      *reinterpret_cast<uint4*>(&bs[o * BSS + g * 8]) =
          *reinterpret_cast<const uint4*>(W + o * 512 + g * 8);
    }
  }
  __syncthreads();

  // ---- layer 0: K=32 (one MFMA step), B = WI from global ----
  {
    bf16x8 a0 = *reinterpret_cast<const bf16x8*>(&xs[(wm * 32 + l15) * XSS + q * 8]);
    bf16x8 a1 = *reinterpret_cast<const bf16x8*>(&xs[(wm * 32 + 16 + l15) * XSS + q * 8]);
    #pragma unroll
    for (int nt = 0; nt < 8; ++nt) {
      int o = wn * 128 + nt * 16 + l15;
      bf16x8 b = *reinterpret_cast<const bf16x8*>(wsu + WI_OFF + o * 32 + q * 8);
      acc[0][nt] = __builtin_amdgcn_mfma_f32_16x16x32_bf16(a0, b, acc[0][nt], 0, 0, 0);
      acc[1][nt] = __builtin_amdgcn_mfma_f32_16x16x32_bf16(a1, b, acc[1][nt], 0, 0, 0);
    }
  }
  __syncthreads();

  // ---- epilogue 0: bias + silu -> xs ----
  #pragma unroll
  for (int nt = 0; nt < 8; ++nt) {
    int col = wn * 128 + nt * 16 + l15;
    float bv = wsf[BI_F + col];
    #pragma unroll
    for (int mt = 0; mt < 2; ++mt) {
      #pragma unroll
      for (int j = 0; j < 4; ++j) {
        int row = wm * 32 + mt * 16 + q * 4 + j;
        float z = acc[mt][nt][j] + bv;
        float h = z / (1.f + __expf(-z));
        xs[row * XSS + col] = f2bf(h);
        acc[mt][nt][j] = 0.f;
      }
    }
  }
  __syncthreads();

  // ---- hidden layers ----
  auto hidden = [&](const unsigned short* W, const unsigned short* Wnext, const float* bias) {
    for (int ks = 0; ks < 16; ++ks) {
      uint4 st[4];
      const bool doStage = (ks < 15) || (Wnext != nullptr);
      const unsigned short* Wp = (ks < 15) ? W : Wnext;
      const int k0n = (ks < 15) ? (ks + 1) * 32 : 0;
      if (doStage) {
        #pragma unroll
        for (int c = 0; c < 4; ++c) {
          int id = tid + c * 512; int o = id >> 2, g = id & 3;
          st[c] = *reinterpret_cast<const uint4*>(Wp + o * 512 + k0n + g * 8);
        }
      }
      const unsigned short* bb = &bs[(ks & 1) * 512 * BSS];
      const int k0 = ks * 32;
      bf16x8 a0 = *reinterpret_cast<const bf16x8*>(&xs[(wm * 32 + l15) * XSS + k0 + q * 8]);
      bf16x8 a1 = *reinterpret_cast<const bf16x8*>(&xs[(wm * 32 + 16 + l15) * XSS + k0 + q * 8]);
      #pragma unroll
      for (int nt = 0; nt < 8; ++nt) {
        bf16x8 b = *reinterpret_cast<const bf16x8*>(&bb[(wn * 128 + nt * 16 + l15) * BSS + q * 8]);
        acc[0][nt] = __builtin_amdgcn_mfma_f32_16x16x32_bf16(a0, b, acc[0][nt], 0, 0, 0);
        acc[1][nt] = __builtin_amdgcn_mfma_f32_16x16x32_bf16(a1, b, acc[1][nt], 0, 0, 0);
      }
      if (doStage) {
        unsigned short* db = &bs[((ks + 1) & 1) * 512 * BSS];
        #pragma unroll
        for (int c = 0; c < 4; ++c) {
          int id = tid + c * 512; int o = id >> 2, g = id & 3;
          *reinterpret_cast<uint4*>(&db[o * BSS + g * 8]) = st[c];
        }
      }
      __syncthreads();
    }
    // epilogue: bias + relu -> xs
    #pragma unroll
    for (int nt = 0; nt < 8; ++nt) {
      int col = wn * 128 + nt * 16 + l15;
      float bv = bias[col];
      #pragma unroll
      for (int mt = 0; mt < 2; ++mt) {
        #pragma unroll
        for (int j = 0; j < 4; ++j) {
          int row = wm * 32 + mt * 16 + q * 4 + j;
          float z = acc[mt][nt][j] + bv;
          xs[row * XSS + col] = f2bf(fmaxf(z, 0.f));
          acc[mt][nt][j] = 0.f;
        }
      }
    }
    __syncthreads();
  };

  hidden(wsu + WH_OFF,          wsu + WH_OFF + 262144, wsf + BH_F);
  hidden(wsu + WH_OFF + 262144, nullptr,               wsf + BH_F + 512);

  // ---- output layer: waves 0..3, N=32 (o padded) ----
  f32x4 oacc[2];
  { f32x4 z = {0.f, 0.f, 0.f, 0.f}; oacc[0] = z; oacc[1] = z; }
  if (wid < 4) {
    for (int ks = 0; ks < 16; ++ks) {
      bf16x8 a = *reinterpret_cast<const bf16x8*>(&xs[(wid * 16 + l15) * XSS + ks * 32 + q * 8]);
      #pragma unroll
      for (int nt = 0; nt < 2; ++nt) {
        int o = nt * 16 + l15;
        bf16x8 b = *reinterpret_cast<const bf16x8*>(wsu + WO_OFF + o * 512 + ks * 32 + q * 8);
        oacc[nt] = __builtin_amdgcn_mfma_f32_16x16x32_bf16(a, b, oacc[nt], 0, 0, 0);
      }
    }
    #pragma unroll
    for (int nt = 0; nt < 2; ++nt) {
      #pragma unroll
      for (int j = 0; j < 4; ++j) {
        int o = nt * 16 + l15;
        int row = wid * 16 + q * 4 + j;
        if (o <= n) {
          float val = (oacc[nt][j] + wsf[BO_F + o]) * scaleS[row];
          size_t gr = (size_t)blk * MT + row;
          float cv = fminf(fmaxf(val, -2.f), 2.f);
          Xout[gr * (n + 1) + o] = val;
          Xcout[gr * (n + 1) + o] = cv;
          xo[row * 20 + o] = val;
        }
      }
    }
  }
  __syncthreads();

  // ---- distortion + squared-error partials (threads 0..63, wave 0) ----
  if (tid < MT) {
    const int r = tid;
    const size_t gr = (size_t)blk * MT + r;
    float x[17], cx[17];
    #pragma unroll
    for (int i = 0; i < 17; ++i) {
      float v = (i <= n) ? xo[r * 20 + i] : 0.f;
      x[i] = v; cx[i] = fminf(fmaxf(v, -2.f), 2.f);
    }
    float e = 0.f, ec = 0.f;
    #pragma unroll
    for (int k = 1; k <= 16; ++k) {
      if (k <= n) {
        float d = 0.f, dc = 0.f;
        #pragma unroll
        for (int i = 0; i + k <= 16; ++i) {
          if (i + k <= n) { d += x[i] * x[i + k]; dc += cx[i] * cx[i + k]; }
        }
        float tvv = T[gr * n + (n - k)];
        float r1 = d - tvv, r2 = dc - tvv;
        e += r1 * r1; ec += r2 * r2;
      }
    }
    #pragma unroll
    for (int off = 32; off; off >>= 1) { e += __shfl_down(e, off); ec += __shfl_down(ec, off); }
    if (lane == 0) { atomicAdd(&errAcc[0], e); atomicAdd(&errAcc[1], ec); }
  }
}

__global__ void finalize_kernel(const float* __restrict__ errAcc, float* __restrict__ e0,
                                float* __restrict__ e1, float inv)
{
  e0[0] = errAcc[0] * inv;
  e1[0] = errAcc[1] * inv;
}

extern "C" void kernel_launch(void* const* d_in, const int* in_sizes, int n_in,
                              void* d_out, int out_size, void* d_ws, size_t ws_size,
                              hipStream_t stream)
{
  const float* T       = (const float*)d_in[0];
  const int*   variant = (const int*)d_in[2];
  const float* w_in    = (const float*)d_in[3];
  const float* b_in    = (const float*)d_in[4];
  const float* w_hid   = (const float*)d_in[5];
  const float* b_hid   = (const float*)d_in[6];
  const float* w_out   = (const float*)d_in[7];
  const float* b_out   = (const float*)d_in[8];
  const int n = in_sizes[0] / BATCH;

  unsigned short* wsu = (unsigned short*)d_ws;
  float* wsf = (float*)((char*)d_ws + (size_t)WS_USH * 2);
  float* out = (float*)d_out;
  const size_t xe = (size_t)BATCH * (n + 1);
  float* Xo  = out;
  float* eP  = out + xe;
  float* Xc  = out + xe + 1;
  float* ecP = out + 2 * xe + 1;

  const int prepBlocks = (PREP_TOTAL + 255) / 256;
  prep_kernel<<<prepBlocks, 256, 0, stream>>>(w_in, b_in, w_hid, b_hid, w_out, b_out,
                                              variant, n, wsu, wsf);
  if (n == 16)
    fused_kernel<16><<<BATCH / MT, 512, 0, stream>>>(T, wsu, wsf, Xo, Xc, wsf + ERR_F, n);
  else
    fused_kernel<0><<<BATCH / MT, 512, 0, stream>>>(T, wsu, wsf, Xo, Xc, wsf + ERR_F, n);
  finalize_kernel<<<1, 1, 0, stream>>>(wsf + ERR_F, eP, ecP, 1.f / (float)((size_t)BATCH * n));
}

// Round 2
// 163.325 us; speedup vs baseline: 1.0268x; 1.0268x over previous
//
#include <hip/hip_runtime.h>

#define BATCH 65536
#define MT 64                 // rows per block

typedef unsigned short u16;
typedef __bf16 bf16x8 __attribute__((ext_vector_type(8)));
typedef float f32x4 __attribute__((ext_vector_type(4)));

// d_ws layout (u16 element offsets) — fragment-native weight layouts:
//   W'[K32][col][g][e]: element (col, k) at [K32][col][k>>3 & 3][k&7], k = K32*32+g*8+e
#define WI_OFF 0              // [1][512][4][8]   (k>=16 zero)
#define WH_OFF 16384          // [2][16][512][4][8]
#define WO_OFF 540672         // [16][32][4][8]   (cols o padded 17->32)
#define WS_USH 557056
// float region at (char*)ws + WS_USH*2
#define BI_F 0
#define BH_F 512
#define BO_F 1536
#define ERR_F 1568
#define PREP_WH 65536
#define PREP_WI 2048
#define PREP_WO 2048
#define PREP_SC 1570
#define PREP_TOTAL (PREP_WH + PREP_WI + PREP_WO + PREP_SC)

__device__ inline u16 f2bf(float f) {
  union { float f; unsigned u; } v; v.f = f;
  unsigned u = v.u + 0x7fffu + ((v.u >> 16) & 1u);   // RNE
  return (u16)(u >> 16);
}

__global__ void prep_kernel(const float* __restrict__ w_in, const float* __restrict__ b_in,
                            const float* __restrict__ w_hid, const float* __restrict__ b_hid,
                            const float* __restrict__ w_out, const float* __restrict__ b_out,
                            const int* __restrict__ variant, int n,
                            u16* __restrict__ wsu, float* __restrict__ wsf)
{
  const int model = (n - 5) * 16 + variant[0];
  const int i = blockIdx.x * 256 + threadIdx.x;
  if (i < PREP_WH) {
    // W'h: dest elems [i*8 .. i*8+8) = w_hid[model][l][col][K32*32+g*8 ..+8)
    int g = i & 3, col = (i >> 2) & 511, K32 = (i >> 11) & 15, l = i >> 15;
    const float* src = w_hid + (size_t)model * 524288 + (size_t)l * 262144 + col * 512 + K32 * 32 + g * 8;
    u16* dst = wsu + WH_OFF + (size_t)i * 8;
    #pragma unroll
    for (int e = 0; e < 8; ++e) dst[e] = f2bf(src[e]);
  } else if (i < PREP_WH + PREP_WI) {
    int j = i - PREP_WH;
    int g = j & 3, col = j >> 2;
    u16* dst = wsu + WI_OFF + (size_t)j * 8;
    #pragma unroll
    for (int e = 0; e < 8; ++e) {
      int k = g * 8 + e;
      dst[e] = (k < 16) ? f2bf(w_in[(size_t)model * 8192 + col * 16 + k]) : (u16)0;
    }
  } else if (i < PREP_WH + PREP_WI + PREP_WO) {
    int j = i - PREP_WH - PREP_WI;
    int g = j & 3, col = (j >> 2) & 31, K32 = j >> 7;
    u16* dst = wsu + WO_OFF + (size_t)j * 8;
    #pragma unroll
    for (int e = 0; e < 8; ++e) {
      int k = K32 * 32 + g * 8 + e;
      dst[e] = (col < 17) ? f2bf(w_out[(size_t)model * 8704 + col * 512 + k]) : (u16)0;
    }
  } else if (i < PREP_TOTAL) {
    int j = i - PREP_WH - PREP_WI - PREP_WO;
    if (j < 512)       wsf[BI_F + j] = b_in[(size_t)model * 512 + j];
    else if (j < 1536) wsf[BH_F + (j - 512)] = b_hid[(size_t)model * 1024 + (j - 512)];
    else if (j < 1568) { int o = j - 1536; wsf[BO_F + o] = (o < 17) ? b_out[(size_t)model * 17 + o] : 0.f; }
    else               wsf[ERR_F + (j - 1568)] = 0.f;
  }
}

template<int CN>
__global__ __launch_bounds__(512, 4) void fused_kernel(
    const float* __restrict__ T, const u16* __restrict__ wsu,
    const float* __restrict__ wsf, float* __restrict__ Xout, float* __restrict__ Xcout,
    float* __restrict__ errAcc, int n_arg)
{
  const int n = CN ? CN : n_arg;
  __shared__ u16 xs[MT * 512];       // 64 KiB, XOR-swizzled: byte = row*1024 + (2k ^ ((row&15)<<4))
  __shared__ float xo[MT * 20];      // X_hat rows for distortion
  __shared__ float scaleS[MT];
  __shared__ float ered[8][2];

  const int tid = threadIdx.x;
  const int blk = blockIdx.x;
  const int lane = tid & 63;
  const int wid = tid >> 6;
  const int l15 = lane & 15;
  const int q = lane >> 4;           // 0..3
  const int c0 = wid * 64;           // wave's output-column base (hidden layers)
  char* xb = (char*)xs;

  auto st16 = [&](int row, int col, u16 v) {
    *(u16*)(xb + row * 1024 + ((col * 2) ^ ((row & 15) << 4))) = v;
  };
  auto rdA = [&](int row, int kbyte) -> bf16x8 {
    return *reinterpret_cast<const bf16x8*>(xb + row * 1024 + (kbyte ^ ((row & 15) << 4)));
  };

  // ---- prologue: T load + normalize; 8 threads/row ----
  {
    const int r = tid >> 3, j = tid & 7;
    const size_t gr = (size_t)blk * MT + r;
    const float* tp = T + gr * n;
    const int k0 = 2 * j, k1 = 2 * j + 1;
    float v0 = (k0 < n) ? tp[k0] : 0.f;
    float v1 = (k1 < n) ? tp[k1] : 0.f;
    float ss = v0 * v0 + v1 * v1;
    ss += __shfl_xor(ss, 1); ss += __shfl_xor(ss, 2); ss += __shfl_xor(ss, 4);
    float norm = sqrtf(ss < 1e-12f ? 1e-12f : ss);
    float rn = 1.f / norm;
    if (j == 0) scaleS[r] = sqrtf(norm);
    st16(r, k0, f2bf(v0 * rn));
    st16(r, k1, f2bf(v1 * rn));
    st16(r, 16 + k0, 0);
    st16(r, 16 + k1, 0);
  }
  __syncthreads();

  // ---- generic dense layer: out[64][512] += act(xs @ W'^T + b), B direct-from-global ----
  // Wp: fragment-native weights; NK: K32 step count; act: 0=silu 1=relu
  auto dense = [&](const u16* __restrict__ Wp, int NK, const float* __restrict__ bias, int act) {
    f32x4 acc[4][4];
    #pragma unroll
    for (int a = 0; a < 4; ++a)
      #pragma unroll
      for (int b = 0; b < 4; ++b) { f32x4 z = {0.f, 0.f, 0.f, 0.f}; acc[a][b] = z; }

    const int bofs = (c0 + l15) * 32 + q * 8;       // lane's elem offset within a K32 block
    uint4 bb[4];
    #pragma unroll
    for (int ct = 0; ct < 4; ++ct)
      bb[ct] = *reinterpret_cast<const uint4*>(Wp + bofs + ct * 512);

    for (int K32 = 0; K32 < NK; ++K32) {
      uint4 bn[4];
      if (K32 + 1 < NK) {
        const u16* Wn = Wp + (K32 + 1) * 16384 + bofs;
        #pragma unroll
        for (int ct = 0; ct < 4; ++ct)
          bn[ct] = *reinterpret_cast<const uint4*>(Wn + ct * 512);
      }
      const int kbyte = K32 * 64 + q * 16;
      #pragma unroll
      for (int mt = 0; mt < 4; ++mt) {
        bf16x8 a = rdA(mt * 16 + l15, kbyte);
        #pragma unroll
        for (int ct = 0; ct < 4; ++ct)
          acc[mt][ct] = __builtin_amdgcn_mfma_f32_16x16x32_bf16(
              a, __builtin_bit_cast(bf16x8, bb[ct]), acc[mt][ct], 0, 0, 0);
      }
      if (K32 + 1 < NK) {
        #pragma unroll
        for (int ct = 0; ct < 4; ++ct) bb[ct] = bn[ct];
      }
    }
    __syncthreads();   // everyone done READING xs

    float bv[4];
    #pragma unroll
    for (int ct = 0; ct < 4; ++ct) bv[ct] = bias[c0 + ct * 16 + l15];
    #pragma unroll
    for (int mt = 0; mt < 4; ++mt)
      #pragma unroll
      for (int ct = 0; ct < 4; ++ct)
        #pragma unroll
        for (int j = 0; j < 4; ++j) {
          int row = mt * 16 + q * 4 + j;
          float z = acc[mt][ct][j] + bv[ct];
          float h = act ? fmaxf(z, 0.f) : z / (1.f + __expf(-z));
          st16(row, c0 + ct * 16 + l15, f2bf(h));
        }
    __syncthreads();   // xs updated for next layer
  };

  dense(wsu + WI_OFF, 1, wsf + BI_F, 0);
  dense(wsu + WH_OFF, 16, wsf + BH_F, 1);
  dense(wsu + WH_OFF + 262144, 16, wsf + BH_F + 512, 1);

  // ---- output layer: waves 0..3, wave w owns rows w*16..+16, 32 padded cols ----
  if (wid < 4) {
    f32x4 oacc[2];
    { f32x4 z = {0.f, 0.f, 0.f, 0.f}; oacc[0] = z; oacc[1] = z; }
    const int bofs2 = l15 * 32 + q * 8;
    uint4 ob[2];
    #pragma unroll
    for (int ct = 0; ct < 2; ++ct)
      ob[ct] = *reinterpret_cast<const uint4*>(wsu + WO_OFF + bofs2 + ct * 512);
    for (int K32 = 0; K32 < 16; ++K32) {
      uint4 on[2];
      if (K32 < 15) {
        const u16* Wn = wsu + WO_OFF + (K32 + 1) * 1024 + bofs2;
        #pragma unroll
        for (int ct = 0; ct < 2; ++ct)
          on[ct] = *reinterpret_cast<const uint4*>(Wn + ct * 512);
      }
      bf16x8 a = rdA(wid * 16 + l15, K32 * 64 + q * 16);
      #pragma unroll
      for (int ct = 0; ct < 2; ++ct)
        oacc[ct] = __builtin_amdgcn_mfma_f32_16x16x32_bf16(
            a, __builtin_bit_cast(bf16x8, ob[ct]), oacc[ct], 0, 0, 0);
      if (K32 < 15) { ob[0] = on[0]; ob[1] = on[1]; }
    }
    #pragma unroll
    for (int ct = 0; ct < 2; ++ct)
      #pragma unroll
      for (int j = 0; j < 4; ++j) {
        int o = ct * 16 + l15;
        int row = wid * 16 + q * 4 + j;
        if (o <= n) {
          float val = (oacc[ct][j] + wsf[BO_F + o]) * scaleS[row];
          size_t gr = (size_t)blk * MT + row;
          float cv = fminf(fmaxf(val, -2.f), 2.f);
          Xout[gr * (n + 1) + o] = val;
          Xcout[gr * (n + 1) + o] = cv;
          xo[row * 20 + o] = val;
        }
      }
  }
  __syncthreads();

  // ---- distortion + squared-error partials: 8 threads/row ----
  {
    const int r = tid >> 3, j = tid & 7;
    const size_t gr = (size_t)blk * MT + r;
    float x[17], cx[17];
    #pragma unroll
    for (int i = 0; i < 17; ++i) {
      float v = (i <= n) ? xo[r * 20 + i] : 0.f;
      x[i] = v; cx[i] = fminf(fmaxf(v, -2.f), 2.f);
    }
    float e = 0.f, ec = 0.f;
    #pragma unroll
    for (int kk = 0; kk < 2; ++kk) {
      int k = j + 1 + kk * 8;
      if (k <= n) {
        float d = 0.f, dc = 0.f;
        #pragma unroll
        for (int i = 0; i < 16; ++i) {
          if (i + k <= 16) {
            if (i + k <= n) { d += x[i] * x[i + k]; dc += cx[i] * cx[i + k]; }
          }
        }
        float tvv = T[gr * n + (n - k)];
        float r1 = d - tvv, r2 = dc - tvv;
        e += r1 * r1; ec += r2 * r2;
      }
    }
    e += __shfl_xor(e, 1);  ec += __shfl_xor(ec, 1);
    e += __shfl_xor(e, 2);  ec += __shfl_xor(ec, 2);
    e += __shfl_xor(e, 4);  ec += __shfl_xor(ec, 4);
    e += __shfl_xor(e, 8);  ec += __shfl_xor(ec, 8);
    e += __shfl_xor(e, 16); ec += __shfl_xor(ec, 16);
    e += __shfl_xor(e, 32); ec += __shfl_xor(ec, 32);
    if (lane == 0) { ered[wid][0] = e; ered[wid][1] = ec; }
  }
  __syncthreads();
  if (tid == 0) {
    float e = 0.f, ec = 0.f;
    #pragma unroll
    for (int w = 0; w < 8; ++w) { e += ered[w][0]; ec += ered[w][1]; }
    atomicAdd(&errAcc[0], e);
    atomicAdd(&errAcc[1], ec);
  }
}

__global__ void finalize_kernel(const float* __restrict__ errAcc, float* __restrict__ e0,
                                float* __restrict__ e1, float inv)
{
  e0[0] = errAcc[0] * inv;
  e1[0] = errAcc[1] * inv;
}

extern "C" void kernel_launch(void* const* d_in, const int* in_sizes, int n_in,
                              void* d_out, int out_size, void* d_ws, size_t ws_size,
                              hipStream_t stream)
{
  const float* T       = (const float*)d_in[0];
  const int*   variant = (const int*)d_in[2];
  const float* w_in    = (const float*)d_in[3];
  const float* b_in    = (const float*)d_in[4];
  const float* w_hid   = (const float*)d_in[5];
  const float* b_hid   = (const float*)d_in[6];
  const float* w_out   = (const float*)d_in[7];
  const float* b_out   = (const float*)d_in[8];
  const int n = in_sizes[0] / BATCH;

  u16* wsu = (u16*)d_ws;
  float* wsf = (float*)((char*)d_ws + (size_t)WS_USH * 2);
  float* out = (float*)d_out;
  const size_t xe = (size_t)BATCH * (n + 1);
  float* Xo  = out;
  float* eP  = out + xe;
  float* Xc  = out + xe + 1;
  float* ecP = out + 2 * xe + 1;

  const int prepBlocks = (PREP_TOTAL + 255) / 256;
  prep_kernel<<<prepBlocks, 256, 0, stream>>>(w_in, b_in, w_hid, b_hid, w_out, b_out,
                                              variant, n, wsu, wsf);
  if (n == 16)
    fused_kernel<16><<<BATCH / MT, 512, 0, stream>>>(T, wsu, wsf, Xo, Xc, wsf + ERR_F, n);
  else
    fused_kernel<0><<<BATCH / MT, 512, 0, stream>>>(T, wsu, wsf, Xo, Xc, wsf + ERR_F, n);
  finalize_kernel<<<1, 1, 0, stream>>>(wsf + ERR_F, eP, ecP, 1.f / (float)((size_t)BATCH * n));
}

// Round 3
// 138.982 us; speedup vs baseline: 1.2066x; 1.1752x over previous
//
#include <hip/hip_runtime.h>

#define BATCH 65536
#define MT 64                 // rows per block

typedef unsigned short u16;
typedef __bf16 bf16x8 __attribute__((ext_vector_type(8)));
typedef float f32x4 __attribute__((ext_vector_type(4)));

// d_ws layout (u16 element offsets) — fragment-native weight layouts:
//   W'[K32][col][g][e]: element (col, k) at [K32][col][k>>3 & 3][k&7], k = K32*32+g*8+e
#define WI_OFF 0              // [1][512][4][8]   (k>=16 zero)
#define WH_OFF 16384          // [2][16][512][4][8]
#define WO_OFF 540672         // [16][32][4][8]   (cols o padded 17->32)
#define WS_USH 557056
// float region at (char*)ws + WS_USH*2
#define BI_F 0
#define BH_F 512
#define BO_F 1536
#define ERR_F 1568
#define PREP_WH 65536
#define PREP_WI 2048
#define PREP_WO 2048
#define PREP_SC 1570
#define PREP_TOTAL (PREP_WH + PREP_WI + PREP_WO + PREP_SC)

__device__ inline u16 f2bf(float f) {
  union { float f; unsigned u; } v; v.f = f;
  unsigned u = v.u + 0x7fffu + ((v.u >> 16) & 1u);   // RNE
  return (u16)(u >> 16);
}

__global__ void prep_kernel(const float* __restrict__ w_in, const float* __restrict__ b_in,
                            const float* __restrict__ w_hid, const float* __restrict__ b_hid,
                            const float* __restrict__ w_out, const float* __restrict__ b_out,
                            const int* __restrict__ variant, int n,
                            u16* __restrict__ wsu, float* __restrict__ wsf)
{
  const int model = (n - 5) * 16 + variant[0];
  const int i = blockIdx.x * 256 + threadIdx.x;
  if (i < PREP_WH) {
    int g = i & 3, col = (i >> 2) & 511, K32 = (i >> 11) & 15, l = i >> 15;
    const float* src = w_hid + (size_t)model * 524288 + (size_t)l * 262144 + col * 512 + K32 * 32 + g * 8;
    u16* dst = wsu + WH_OFF + (size_t)i * 8;
    #pragma unroll
    for (int e = 0; e < 8; ++e) dst[e] = f2bf(src[e]);
  } else if (i < PREP_WH + PREP_WI) {
    int j = i - PREP_WH;
    int g = j & 3, col = j >> 2;
    u16* dst = wsu + WI_OFF + (size_t)j * 8;
    #pragma unroll
    for (int e = 0; e < 8; ++e) {
      int k = g * 8 + e;
      dst[e] = (k < 16) ? f2bf(w_in[(size_t)model * 8192 + col * 16 + k]) : (u16)0;
    }
  } else if (i < PREP_WH + PREP_WI + PREP_WO) {
    int j = i - PREP_WH - PREP_WI;
    int g = j & 3, col = (j >> 2) & 31, K32 = j >> 7;
    u16* dst = wsu + WO_OFF + (size_t)j * 8;
    #pragma unroll
    for (int e = 0; e < 8; ++e) {
      int k = K32 * 32 + g * 8 + e;
      dst[e] = (col < 17) ? f2bf(w_out[(size_t)model * 8704 + col * 512 + k]) : (u16)0;
    }
  } else if (i < PREP_TOTAL) {
    int j = i - PREP_WH - PREP_WI - PREP_WO;
    if (j < 512)       wsf[BI_F + j] = b_in[(size_t)model * 512 + j];
    else if (j < 1536) wsf[BH_F + (j - 512)] = b_hid[(size_t)model * 1024 + (j - 512)];
    else if (j < 1568) { int o = j - 1536; wsf[BO_F + o] = (o < 17) ? b_out[(size_t)model * 17 + o] : 0.f; }
    else               wsf[ERR_F + (j - 1568)] = 0.f;
  }
}

// xs layout: byte = row*1024 + ((col*2) ^ ((row&15)<<4))
__device__ __forceinline__ bf16x8 rdA(const char* xb, int row, int kbyte) {
  return *reinterpret_cast<const bf16x8*>(xb + row * 1024 + (kbyte ^ ((row & 15) << 4)));
}
__device__ __forceinline__ void st16(char* xb, int row, int col, u16 v) {
  *(u16*)(xb + row * 1024 + ((col * 2) ^ ((row & 15) << 4))) = v;
}

// One dense 512->512 (or 32-K) layer: xs[64][512] -> xs[64][512], B direct from global.
// NK: compile-time K32 step count. act: 0=silu, 1=relu.
template<int NK>
__device__ __forceinline__ void dense_layer(const u16* __restrict__ Wp,
                                            const float* __restrict__ bias, int act,
                                            char* xb, int l15, int q, int c0)
{
  f32x4 acc[4][4];
  #pragma unroll
  for (int a = 0; a < 4; ++a)
    #pragma unroll
    for (int b = 0; b < 4; ++b) { f32x4 z = {0.f, 0.f, 0.f, 0.f}; acc[a][b] = z; }

  const u16* Wl = Wp + (c0 + l15) * 32 + q * 8;   // lane's base within a K32 block
  uint4 b0[4], b1[4];
  #pragma unroll
  for (int ct = 0; ct < 4; ++ct)
    b0[ct] = *reinterpret_cast<const uint4*>(Wl + ct * 512);

  #pragma unroll
  for (int K2 = 0; K2 < NK; K2 += 2) {
    if (K2 + 1 < NK) {
      #pragma unroll
      for (int ct = 0; ct < 4; ++ct)
        b1[ct] = *reinterpret_cast<const uint4*>(Wl + (K2 + 1) * 16384 + ct * 512);
    }
    {
      const int kbyte = K2 * 64 + q * 16;
      #pragma unroll
      for (int mt = 0; mt < 4; ++mt) {
        bf16x8 a = rdA(xb, mt * 16 + l15, kbyte);
        #pragma unroll
        for (int ct = 0; ct < 4; ++ct)
          acc[mt][ct] = __builtin_amdgcn_mfma_f32_16x16x32_bf16(
              a, __builtin_bit_cast(bf16x8, b0[ct]), acc[mt][ct], 0, 0, 0);
      }
    }
    if (K2 + 1 < NK) {
      if (K2 + 2 < NK) {
        #pragma unroll
        for (int ct = 0; ct < 4; ++ct)
          b0[ct] = *reinterpret_cast<const uint4*>(Wl + (K2 + 2) * 16384 + ct * 512);
      }
      const int kbyte = (K2 + 1) * 64 + q * 16;
      #pragma unroll
      for (int mt = 0; mt < 4; ++mt) {
        bf16x8 a = rdA(xb, mt * 16 + l15, kbyte);
        #pragma unroll
        for (int ct = 0; ct < 4; ++ct)
          acc[mt][ct] = __builtin_amdgcn_mfma_f32_16x16x32_bf16(
              a, __builtin_bit_cast(bf16x8, b1[ct]), acc[mt][ct], 0, 0, 0);
      }
    }
  }
  __syncthreads();   // all waves done READING xs

  float bv[4];
  #pragma unroll
  for (int ct = 0; ct < 4; ++ct) bv[ct] = bias[c0 + ct * 16 + l15];
  #pragma unroll
  for (int mt = 0; mt < 4; ++mt)
    #pragma unroll
    for (int ct = 0; ct < 4; ++ct)
      #pragma unroll
      for (int j = 0; j < 4; ++j) {
        int row = mt * 16 + q * 4 + j;
        float z = acc[mt][ct][j] + bv[ct];
        float h = act ? fmaxf(z, 0.f) : z / (1.f + __expf(-z));
        st16(xb, row, c0 + ct * 16 + l15, f2bf(h));
      }
  __syncthreads();   // xs updated for next layer
}

template<int CN>
__global__ __launch_bounds__(512, 2) void fused_kernel(
    const float* __restrict__ T, const u16* __restrict__ wsu,
    const float* __restrict__ wsf, float* __restrict__ Xout, float* __restrict__ Xcout,
    float* __restrict__ errAcc, int n_arg)
{
  const int n = CN ? CN : n_arg;
  __shared__ u16 xs[MT * 512];       // 64 KiB, XOR-swizzled
  __shared__ float xo[MT * 20];      // X_hat rows for distortion
  __shared__ float scaleS[MT];
  __shared__ float ered[8][2];

  const int tid = threadIdx.x;
  const int blk = blockIdx.x;
  const int lane = tid & 63;
  const int wid = tid >> 6;
  const int l15 = lane & 15;
  const int q = lane >> 4;           // 0..3
  const int c0 = wid * 64;           // wave's output-column base (hidden layers)
  char* xb = (char*)xs;

  // ---- prologue: T load + normalize; 8 threads/row ----
  {
    const int r = tid >> 3, j = tid & 7;
    const size_t gr = (size_t)blk * MT + r;
    const float* tp = T + gr * n;
    const int k0 = 2 * j, k1 = 2 * j + 1;
    float v0 = (k0 < n) ? tp[k0] : 0.f;
    float v1 = (k1 < n) ? tp[k1] : 0.f;
    float ss = v0 * v0 + v1 * v1;
    ss += __shfl_xor(ss, 1); ss += __shfl_xor(ss, 2); ss += __shfl_xor(ss, 4);
    float norm = sqrtf(ss < 1e-12f ? 1e-12f : ss);
    float rn = 1.f / norm;
    if (j == 0) scaleS[r] = sqrtf(norm);
    st16(xb, r, k0, f2bf(v0 * rn));
    st16(xb, r, k1, f2bf(v1 * rn));
    st16(xb, r, 16 + k0, 0);
    st16(xb, r, 16 + k1, 0);
  }
  __syncthreads();

  dense_layer<1 >(wsu + WI_OFF,          wsf + BI_F,       0, xb, l15, q, c0);
  dense_layer<16>(wsu + WH_OFF,          wsf + BH_F,       1, xb, l15, q, c0);
  dense_layer<16>(wsu + WH_OFF + 262144, wsf + BH_F + 512, 1, xb, l15, q, c0);

  // ---- output layer: waves 0..3, wave w owns rows w*16..+16, 32 padded cols ----
  if (wid < 4) {
    f32x4 oacc[2];
    { f32x4 z = {0.f, 0.f, 0.f, 0.f}; oacc[0] = z; oacc[1] = z; }
    const int bofs2 = l15 * 32 + q * 8;
    uint4 ob[2], on[2];
    #pragma unroll
    for (int ct = 0; ct < 2; ++ct)
      ob[ct] = *reinterpret_cast<const uint4*>(wsu + WO_OFF + bofs2 + ct * 512);
    #pragma unroll
    for (int K2 = 0; K2 < 16; K2 += 2) {
      #pragma unroll
      for (int ct = 0; ct < 2; ++ct)
        on[ct] = *reinterpret_cast<const uint4*>(wsu + WO_OFF + (K2 + 1) * 1024 + bofs2 + ct * 512);
      {
        bf16x8 a = rdA(xb, wid * 16 + l15, K2 * 64 + q * 16);
        #pragma unroll
        for (int ct = 0; ct < 2; ++ct)
          oacc[ct] = __builtin_amdgcn_mfma_f32_16x16x32_bf16(
              a, __builtin_bit_cast(bf16x8, ob[ct]), oacc[ct], 0, 0, 0);
      }
      if (K2 + 2 < 16) {
        #pragma unroll
        for (int ct = 0; ct < 2; ++ct)
          ob[ct] = *reinterpret_cast<const uint4*>(wsu + WO_OFF + (K2 + 2) * 1024 + bofs2 + ct * 512);
      }
      {
        bf16x8 a = rdA(xb, wid * 16 + l15, (K2 + 1) * 64 + q * 16);
        #pragma unroll
        for (int ct = 0; ct < 2; ++ct)
          oacc[ct] = __builtin_amdgcn_mfma_f32_16x16x32_bf16(
              a, __builtin_bit_cast(bf16x8, on[ct]), oacc[ct], 0, 0, 0);
      }
    }
    #pragma unroll
    for (int ct = 0; ct < 2; ++ct)
      #pragma unroll
      for (int j = 0; j < 4; ++j) {
        int o = ct * 16 + l15;
        int row = wid * 16 + q * 4 + j;
        if (o <= n) {
          float val = (oacc[ct][j] + wsf[BO_F + o]) * scaleS[row];
          size_t gr = (size_t)blk * MT + row;
          float cv = fminf(fmaxf(val, -2.f), 2.f);
          Xout[gr * (n + 1) + o] = val;
          Xcout[gr * (n + 1) + o] = cv;
          xo[row * 20 + o] = val;
        }
      }
  }
  __syncthreads();

  // ---- distortion + squared-error partials: 8 threads/row ----
  {
    const int r = tid >> 3, j = tid & 7;
    const size_t gr = (size_t)blk * MT + r;
    float x[17], cx[17];
    #pragma unroll
    for (int i = 0; i < 17; ++i) {
      float v = (i <= n) ? xo[r * 20 + i] : 0.f;
      x[i] = v; cx[i] = fminf(fmaxf(v, -2.f), 2.f);
    }
    float e = 0.f, ec = 0.f;
    #pragma unroll
    for (int kk = 0; kk < 2; ++kk) {
      int k = j + 1 + kk * 8;
      if (k <= n) {
        float d = 0.f, dc = 0.f;
        #pragma unroll
        for (int i = 0; i < 16; ++i) {
          if (i + k <= 16) {
            if (i + k <= n) { d += x[i] * x[i + k]; dc += cx[i] * cx[i + k]; }
          }
        }
        float tvv = T[gr * n + (n - k)];
        float r1 = d - tvv, r2 = dc - tvv;
        e += r1 * r1; ec += r2 * r2;
      }
    }
    e += __shfl_xor(e, 1);  ec += __shfl_xor(ec, 1);
    e += __shfl_xor(e, 2);  ec += __shfl_xor(ec, 2);
    e += __shfl_xor(e, 4);  ec += __shfl_xor(ec, 4);
    e += __shfl_xor(e, 8);  ec += __shfl_xor(ec, 8);
    e += __shfl_xor(e, 16); ec += __shfl_xor(ec, 16);
    e += __shfl_xor(e, 32); ec += __shfl_xor(ec, 32);
    if (lane == 0) { ered[wid][0] = e; ered[wid][1] = ec; }
  }
  __syncthreads();
  if (tid == 0) {
    float e = 0.f, ec = 0.f;
    #pragma unroll
    for (int w = 0; w < 8; ++w) { e += ered[w][0]; ec += ered[w][1]; }
    atomicAdd(&errAcc[0], e);
    atomicAdd(&errAcc[1], ec);
  }
}

__global__ void finalize_kernel(const float* __restrict__ errAcc, float* __restrict__ e0,
                                float* __restrict__ e1, float inv)
{
  e0[0] = errAcc[0] * inv;
  e1[0] = errAcc[1] * inv;
}

extern "C" void kernel_launch(void* const* d_in, const int* in_sizes, int n_in,
                              void* d_out, int out_size, void* d_ws, size_t ws_size,
                              hipStream_t stream)
{
  const float* T       = (const float*)d_in[0];
  const int*   variant = (const int*)d_in[2];
  const float* w_in    = (const float*)d_in[3];
  const float* b_in    = (const float*)d_in[4];
  const float* w_hid   = (const float*)d_in[5];
  const float* b_hid   = (const float*)d_in[6];
  const float* w_out   = (const float*)d_in[7];
  const float* b_out   = (const float*)d_in[8];
  const int n = in_sizes[0] / BATCH;

  u16* wsu = (u16*)d_ws;
  float* wsf = (float*)((char*)d_ws + (size_t)WS_USH * 2);
  float* out = (float*)d_out;
  const size_t xe = (size_t)BATCH * (n + 1);
  float* Xo  = out;
  float* eP  = out + xe;
  float* Xc  = out + xe + 1;
  float* ecP = out + 2 * xe + 1;

  const int prepBlocks = (PREP_TOTAL + 255) / 256;
  prep_kernel<<<prepBlocks, 256, 0, stream>>>(w_in, b_in, w_hid, b_hid, w_out, b_out,
                                              variant, n, wsu, wsf);
  if (n == 16)
    fused_kernel<16><<<BATCH / MT, 512, 0, stream>>>(T, wsu, wsf, Xo, Xc, wsf + ERR_F, n);
  else
    fused_kernel<0><<<BATCH / MT, 512, 0, stream>>>(T, wsu, wsf, Xo, Xc, wsf + ERR_F, n);
  finalize_kernel<<<1, 1, 0, stream>>>(wsf + ERR_F, eP, ecP, 1.f / (float)((size_t)BATCH * n));
}